// Round 4
// baseline (92.666 us; speedup 1.0000x reference)
//
#include <hip/hip_runtime.h>
#include <cstdint>

// ---------------------------------------------------------------------------
// QuantumBranch, R7: 2 samples/thread — halve per-sample LDS traffic.
// R6 post-mortem (92.51us): kernel ~24.5us vs 10.8us write floor. Phase 1
// read the full 2KB V per SAMPLE (128 uniform ds_read_b128/thread ~1536cyc
// of LDS pipe per wave; 16 waves/CU => ~11-13us per-CU LDS serialization,
// co-dominant with the write drain). Fix: j-outer loop reads column j of
// Vr/Vi ONCE (8 ds_read_b128) and applies it to TWO samples (64 FMA) ->
// LDS per sample halves, FMA:LDS ratio doubles, LDS pressure drops below
// the write floor. Grid halves to 512 blocks (setup redundancy halves too).
// launch_bounds(256,2): ~150 live VGPR in the matvec, 2 blocks/CU = full
// one-generation residency. Per-sample FMA order / z / softmax / var /
// store math IDENTICAL to R6 (absmax sits exactly at 0.015625).
//
// Math (verified R1-R6): circuit collapses to V = U*diag((-i)^popc),
// z_w = sum_i +/- (r_i^2+s_i^2), r=Re(V)m, s=Im(V)m, m = product-state
// magnitudes from tanh(x)*pi/2. LayerNorm collapses to a 4x4 quadratic
// form: out[b,k] = inv_b*(A[k].q_b + B0[k]) + beta[k].
// ---------------------------------------------------------------------------

// block-shared LDS float offsets
#define WS_VRT 0     // 256: Re(V)^T  [col*16+row]
#define WS_VIT 256   // 256: Im(V)^T
#define WS_A   512   // 256: (W-colmean)*gamma  [k*4+w]
#define WS_B0  768   // 64:  (b-bmean)*gamma
#define WS_G   832   // 16:  G[4][4]
#define WS_g   848   // 4
#define WS_C0  852   // 1
#define WS_Q   864   // 2048: staged q (float4 x 512 samples)
#define WS_INV 2912  // 512:  staged inv
#define WREG   3424  // total floats (13696 B)

__global__ __launch_bounds__(256, 2) void qb_fused(const float* __restrict__ x,
                                                   const float* __restrict__ wts,
                                                   const float* __restrict__ W,
                                                   const float* __restrict__ bias,
                                                   const float* __restrict__ gamma,
                                                   const float* __restrict__ beta,
                                                   float* __restrict__ out) {
    __shared__ __align__(16) float wlds[WREG];
    const int tid  = threadIdx.x;
    const int wv   = tid >> 6;
    const int lane = tid & 63;

    // issue x loads first: HBM latency hides under pre-barrier compute.
    // thread owns local samples (wv*128+lane) and (wv*128+64+lane).
    const int base = blockIdx.x * 512 + wv * 128 + lane;
    const float4 xv0 = ((const float4*)x)[base];
    const float4 xv1 = ((const float4*)x)[base + 64];

    // beta for the store phase: independent of setup, issue before barrier
    const int k4t = lane & 15;
    const float4 Bt4v = ((const float4*)beta)[k4t];

    // ---- pre-barrier: product-state magnitudes for both samples ----
    float m0[16], m1[16];
    {
        const float xa[8] = {xv0.x, xv0.y, xv0.z, xv0.w,
                             xv1.x, xv1.y, xv1.z, xv1.w};
        float c4[8], s4[8];
        #pragma unroll
        for (int w = 0; w < 8; ++w) {
            const float h = tanhf(xa[w]) * 1.5707963267948966f;
            __sincosf(h, &s4[w], &c4[w]);
        }
        {
            const float e01[4] = {c4[0]*c4[1], c4[0]*s4[1], s4[0]*c4[1], s4[0]*s4[1]};
            const float e23[4] = {c4[2]*c4[3], c4[2]*s4[3], s4[2]*c4[3], s4[2]*s4[3]};
            #pragma unroll
            for (int j = 0; j < 16; ++j) m0[j] = e01[j>>2]*e23[j&3];
        }
        {
            const float e01[4] = {c4[4]*c4[5], c4[4]*s4[5], s4[4]*c4[5], s4[4]*s4[5]};
            const float e23[4] = {c4[6]*c4[7], c4[6]*s4[7], s4[6]*c4[7], s4[6]*s4[7]};
            #pragma unroll
            for (int j = 0; j < 16; ++j) m1[j] = e01[j>>2]*e23[j&3];
        }
    }

    // ---- wave 0: unitary -> V^T in block LDS ----
    if (wv == 0) {
        const int row = lane >> 2;
        const int cg  = lane & 3;
        float ur[4], ui[4];   // U[row][4cg+c]
        #pragma unroll
        for (int c = 0; c < 4; ++c) { ur[c] = (row == 4*cg + c) ? 1.f : 0.f; ui[c] = 0.f; }

        #pragma unroll
        for (int l = 0; l < 2; ++l) {
            #pragma unroll
            for (int w = 0; w < 4; ++w) {
                const float ph = wts[l*12 + w*3 + 0];
                const float th = wts[l*12 + w*3 + 1];
                const float om = wts[l*12 + w*3 + 2];
                float st, ct; __sincosf(0.5f*th, &st, &ct);
                float sp, cp; __sincosf(0.5f*(ph+om), &sp, &cp);
                float sm, cm; __sincosf(0.5f*(ph-om), &sm, &cm);
                const float a00r =  cp*ct, a00i = -sp*ct;
                const float a01r = -cm*st, a01i = -sm*st;
                const float a10r =  cm*st, a10i = -sm*st;
                const float a11r =  cp*ct, a11i =  sp*ct;
                const int m8 = 8 >> w;
                const int xm = m8 << 2;           // lane xor mask for row^m8
                const bool hi = (row & m8) != 0;
                #pragma unroll
                for (int c = 0; c < 4; ++c) {
                    const float pr = __shfl_xor(ur[c], xm, 64);
                    const float pi = __shfl_xor(ui[c], xm, 64);
                    float nr, ni;
                    if (!hi) {
                        nr = a00r*ur[c] - a00i*ui[c] + a01r*pr - a01i*pi;
                        ni = a00r*ui[c] + a00i*ur[c] + a01r*pi + a01i*pr;
                    } else {
                        nr = a11r*ur[c] - a11i*ui[c] + a10r*pr - a10i*pi;
                        ni = a11r*ui[c] + a11i*ur[c] + a10r*pi + a10i*pr;
                    }
                    ur[c] = nr; ui[c] = ni;
                }
            }
            const int rr = (l == 0) ? 1 : 2;
            #pragma unroll
            for (int w = 0; w < 4; ++w) {
                const int cmk = 8 >> w;
                const int tmk = 8 >> ((w + rr) & 3);
                const int src = (row & cmk) ? (row ^ tmk) : row;
                const int srcLane = src*4 + cg;
                #pragma unroll
                for (int c = 0; c < 4; ++c) {
                    ur[c] = __shfl(ur[c], srcLane, 64);
                    ui[c] = __shfl(ui[c], srcLane, 64);
                }
            }
        }

        // V = U * diag((-i)^popc(col)); park transposed in block LDS
        #pragma unroll
        for (int c = 0; c < 4; ++c) {
            const int col = 4*cg + c;
            const int p = __popc(col) & 3;
            float vr, vi;
            if (p == 0)      { vr =  ur[c]; vi =  ui[c]; }
            else if (p == 1) { vr =  ui[c]; vi = -ur[c]; }
            else if (p == 2) { vr = -ur[c]; vi = -ui[c]; }
            else             { vr = -ui[c]; vi =  ur[c]; }
            wlds[WS_VRT + col*16 + row] = vr;
            wlds[WS_VIT + col*16 + row] = vi;
        }
    } else if (wv == 1) {
        // ---- wave 1 (concurrent with wave 0): LN constants ----
        const int k = lane;
        const float4 wk = ((const float4*)W)[k];
        const float w0 = wk.x, w1 = wk.y, w2 = wk.z, w3 = wk.w;
        const float bk = bias[k];
        auto wsum = [](float v) {
            #pragma unroll
            for (int o = 32; o; o >>= 1) v += __shfl_xor(v, o, 64);
            return v;
        };
        const float inv64 = 1.f/64.f;
        const float mw0 = wsum(w0)*inv64, mw1 = wsum(w1)*inv64;
        const float mw2 = wsum(w2)*inv64, mw3 = wsum(w3)*inv64;
        const float bm = wsum(bk)*inv64;
        float cc[4] = {w0-mw0, w1-mw1, w2-mw2, w3-mw3};
        const float bc = bk - bm;
        const float gk = gamma[k];
        float4 av;
        av.x = cc[0]*gk; av.y = cc[1]*gk; av.z = cc[2]*gk; av.w = cc[3]*gk;
        ((float4*)(wlds + WS_A))[k] = av;
        wlds[WS_B0 + k] = bc*gk;
        // G is symmetric: 10 wave-sums instead of 16
        #pragma unroll
        for (int a = 0; a < 4; ++a)
            #pragma unroll
            for (int b2 = a; b2 < 4; ++b2) {
                const float s = wsum(cc[a]*cc[b2])*inv64;   // wave-uniform
                if (k == 0) {
                    wlds[WS_G + a*4 + b2] = s;
                    wlds[WS_G + b2*4 + a] = s;
                }
            }
        #pragma unroll
        for (int a = 0; a < 4; ++a) {
            const float s = wsum(bc*cc[a])*inv64;
            if (k == 0) wlds[WS_g + a] = s;
        }
        { const float s = wsum(bc*bc)*inv64; if (k == 0) wlds[WS_C0] = s; }
    }

    __syncthreads();   // the ONLY barrier: setup results now block-visible

    // ---- phase 1: j-outer matvec, V column read ONCE, used for 2 samples ----
    float r0[16], t0[16], r1[16], t1[16];
    #pragma unroll
    for (int i = 0; i < 16; ++i) { r0[i]=0.f; t0[i]=0.f; r1[i]=0.f; t1[i]=0.f; }
    const float4* vr4 = (const float4*)(wlds + WS_VRT);
    const float4* vi4 = (const float4*)(wlds + WS_VIT);
    #pragma unroll
    for (int j = 0; j < 16; ++j) {
        const float mj0 = m0[j];
        const float mj1 = m1[j];
        #pragma unroll
        for (int i4 = 0; i4 < 4; ++i4) {
            const float4 a = vr4[j*4 + i4];   // uniform-address broadcast
            const float4 b = vi4[j*4 + i4];
            r0[i4*4+0] = fmaf(a.x, mj0, r0[i4*4+0]);
            r0[i4*4+1] = fmaf(a.y, mj0, r0[i4*4+1]);
            r0[i4*4+2] = fmaf(a.z, mj0, r0[i4*4+2]);
            r0[i4*4+3] = fmaf(a.w, mj0, r0[i4*4+3]);
            t0[i4*4+0] = fmaf(b.x, mj0, t0[i4*4+0]);
            t0[i4*4+1] = fmaf(b.y, mj0, t0[i4*4+1]);
            t0[i4*4+2] = fmaf(b.z, mj0, t0[i4*4+2]);
            t0[i4*4+3] = fmaf(b.w, mj0, t0[i4*4+3]);
            r1[i4*4+0] = fmaf(a.x, mj1, r1[i4*4+0]);
            r1[i4*4+1] = fmaf(a.y, mj1, r1[i4*4+1]);
            r1[i4*4+2] = fmaf(a.z, mj1, r1[i4*4+2]);
            r1[i4*4+3] = fmaf(a.w, mj1, r1[i4*4+3]);
            t1[i4*4+0] = fmaf(b.x, mj1, t1[i4*4+0]);
            t1[i4*4+1] = fmaf(b.y, mj1, t1[i4*4+1]);
            t1[i4*4+2] = fmaf(b.z, mj1, t1[i4*4+2]);
            t1[i4*4+3] = fmaf(b.w, mj1, t1[i4*4+3]);
        }
    }

    // ---- finish (z -> softmax -> var -> inv), identical math per sample ----
    auto finish = [&](const float* r, const float* si, float4& qo, float& invo) {
        float z0 = 0.f, z1 = 0.f, z2 = 0.f, z3 = 0.f;
        #pragma unroll
        for (int i = 0; i < 16; ++i) {
            const float p = r[i]*r[i] + si[i]*si[i];
            z0 += (i & 8) ? -p : p;
            z1 += (i & 4) ? -p : p;
            z2 += (i & 2) ? -p : p;
            z3 += (i & 1) ? -p : p;
        }
        const float mx = fmaxf(fmaxf(z0, z1), fmaxf(z2, z3));
        const float e0 = __expf(z0-mx), e1 = __expf(z1-mx);
        const float e2 = __expf(z2-mx), e3 = __expf(z3-mx);
        const float rs = 1.f / (e0+e1+e2+e3);
        const float qx = e0*rs, qy = e1*rs, qz = e2*rs, qw = e3*rs;
        float var = wlds[WS_C0];
        {
            const float4 Gs0 = ((const float4*)(wlds + WS_G))[0];
            const float4 Gs1 = ((const float4*)(wlds + WS_G))[1];
            const float4 Gs2 = ((const float4*)(wlds + WS_G))[2];
            const float4 Gs3 = ((const float4*)(wlds + WS_G))[3];
            const float4 gv  = ((const float4*)(wlds + WS_g))[0];
            const float qa[4] = {qx, qy, qz, qw};
            const float4 Gs[4] = {Gs0, Gs1, Gs2, Gs3};
            const float ga[4] = {gv.x, gv.y, gv.z, gv.w};
            #pragma unroll
            for (int a = 0; a < 4; ++a) {
                float t = 2.f * ga[a];
                t = fmaf(Gs[a].x, qa[0], t);
                t = fmaf(Gs[a].y, qa[1], t);
                t = fmaf(Gs[a].z, qa[2], t);
                t = fmaf(Gs[a].w, qa[3], t);
                var = fmaf(qa[a], t, var);
            }
        }
        qo = make_float4(qx, qy, qz, qw);
        invo = rsqrtf(var + 1e-5f);
    };
    float4 q0, q1; float inv0, inv1;
    finish(r0, t0, q0, inv0);
    finish(r1, t1, q1, inv1);

    // ---- stage q/inv in wave-local LDS (no barrier: same-wave RAW is
    //      ordered by lgkmcnt) ----
    ((float4*)(wlds + WS_Q))[wv*128 + lane]      = q0;
    ((float4*)(wlds + WS_Q))[wv*128 + 64 + lane] = q1;
    wlds[WS_INV + wv*128 + lane]      = inv0;
    wlds[WS_INV + wv*128 + 64 + lane] = inv1;

    // ---- phase 2: wave-local coalesced stores, q/inv via LDS broadcast ----
    float4 A4[4];
    #pragma unroll
    for (int u = 0; u < 4; ++u) A4[u] = ((const float4*)(wlds + WS_A))[k4t*4 + u];
    const float4 B04v = ((const float4*)(wlds + WS_B0))[k4t];
    const float B04[4] = {B04v.x, B04v.y, B04v.z, B04v.w};
    const float Bt4[4] = {Bt4v.x, Bt4v.y, Bt4v.z, Bt4v.w};

    // wave wv owns local samples [wv*128, wv*128+128): 32 KB contiguous
    float4* outv = (float4*)out + (size_t)blockIdx.x * 8192 + wv * 2048 + lane;
    const float4* qld = (const float4*)(wlds + WS_Q) + wv*128 + (lane >> 4);
    const float*  ild = wlds + WS_INV + wv*128 + (lane >> 4);
    #pragma unroll
    for (int iter = 0; iter < 32; ++iter) {
        const float4 q  = qld[iter*4];     // 4 addrs/wave, conflict-free
        const float  iv = ild[iter*4];
        float4 o;
        float* op = (float*)&o;
        #pragma unroll
        for (int u = 0; u < 4; ++u) {
            float t = B04[u];
            t = fmaf(A4[u].x, q.x, t);
            t = fmaf(A4[u].y, q.y, t);
            t = fmaf(A4[u].z, q.z, t);
            t = fmaf(A4[u].w, q.w, t);
            op[u] = fmaf(t, iv, Bt4[u]);
        }
        outv[iter*64] = o;
    }
}

extern "C" void kernel_launch(void* const* d_in, const int* in_sizes, int n_in,
                              void* d_out, int out_size, void* d_ws, size_t ws_size,
                              hipStream_t stream) {
    const float* x     = (const float*)d_in[0];
    const float* wts   = (const float*)d_in[1];
    const float* W     = (const float*)d_in[2];
    const float* bias  = (const float*)d_in[3];
    const float* gamma = (const float*)d_in[4];
    const float* beta  = (const float*)d_in[5];
    float* out = (float*)d_out;
    const int B = in_sizes[0] / 4;   // 262144

    hipLaunchKernelGGL(qb_fused, dim3(B / 512), dim3(256), 0, stream,
                       x, wts, W, bias, gamma, beta, out);
}

// Round 5
// 92.385 us; speedup vs baseline: 1.0030x; 1.0030x over previous
//
#include <hip/hip_runtime.h>
#include <cstdint>

// ---------------------------------------------------------------------------
// QuantumBranch, R8: software-pipelined samples — halve the pre-store ramp.
// R7 post-mortem (92.67, neutral vs R6's 92.51): halving per-sample LDS
// traffic changed nothing -> LDS pipe was NOT binding. Cross-round
// calibration (fixed harness ~80us) puts the kernel at ~12.5us vs a 10.9us
// write floor (67MB @ 6.2TB/s); compute is TLP-hidden. The residual is the
// pre-store ramp: all 2-sample compute (~2.5us) ran before ANY store.
// R8 splits post-barrier work into two compute->stage->store passes:
//   matvec(s0) -> finish -> stage -> 16 store iters (first 64-sample half)
//   matvec(s1) -> finish -> stage -> 16 store iters (second half)
// Ramp halves; sample-1 compute overlaps sample-0 store drain. Per-sample
// FMA order / finish / staging / store math bit-identical to R7 (absmax
// sits exactly at 0.015625). If neutral: kernel is at write-floor+ramp,
// declare roofline.
//
// Math (verified R1-R7): circuit collapses to V = U*diag((-i)^popc),
// z_w = sum_i +/- (r_i^2+s_i^2), r=Re(V)m, s=Im(V)m, m = product-state
// magnitudes from tanh(x)*pi/2. LayerNorm collapses to a 4x4 quadratic
// form: out[b,k] = inv_b*(A[k].q_b + B0[k]) + beta[k].
// ---------------------------------------------------------------------------

// block-shared LDS float offsets
#define WS_VRT 0     // 256: Re(V)^T  [col*16+row]
#define WS_VIT 256   // 256: Im(V)^T
#define WS_A   512   // 256: (W-colmean)*gamma  [k*4+w]
#define WS_B0  768   // 64:  (b-bmean)*gamma
#define WS_G   832   // 16:  G[4][4]
#define WS_g   848   // 4
#define WS_C0  852   // 1
#define WS_Q   864   // 2048: staged q (float4 x 512 samples)
#define WS_INV 2912  // 512:  staged inv
#define WREG   3424  // total floats (13696 B)

__global__ __launch_bounds__(256, 2) void qb_fused(const float* __restrict__ x,
                                                   const float* __restrict__ wts,
                                                   const float* __restrict__ W,
                                                   const float* __restrict__ bias,
                                                   const float* __restrict__ gamma,
                                                   const float* __restrict__ beta,
                                                   float* __restrict__ out) {
    __shared__ __align__(16) float wlds[WREG];
    const int tid  = threadIdx.x;
    const int wv   = tid >> 6;
    const int lane = tid & 63;

    // issue x loads first: HBM latency hides under pre-barrier compute.
    // thread owns local samples (wv*128+lane) and (wv*128+64+lane).
    const int base = blockIdx.x * 512 + wv * 128 + lane;
    const float4 xv0 = ((const float4*)x)[base];
    const float4 xv1 = ((const float4*)x)[base + 64];

    // beta for the store phase: independent of setup, issue before barrier
    const int k4t = lane & 15;
    const float4 Bt4v = ((const float4*)beta)[k4t];

    // ---- pre-barrier: product-state magnitudes for both samples ----
    float m0[16], m1[16];
    {
        const float xa[8] = {xv0.x, xv0.y, xv0.z, xv0.w,
                             xv1.x, xv1.y, xv1.z, xv1.w};
        float c4[8], s4[8];
        #pragma unroll
        for (int w = 0; w < 8; ++w) {
            const float h = tanhf(xa[w]) * 1.5707963267948966f;
            __sincosf(h, &s4[w], &c4[w]);
        }
        {
            const float e01[4] = {c4[0]*c4[1], c4[0]*s4[1], s4[0]*c4[1], s4[0]*s4[1]};
            const float e23[4] = {c4[2]*c4[3], c4[2]*s4[3], s4[2]*c4[3], s4[2]*s4[3]};
            #pragma unroll
            for (int j = 0; j < 16; ++j) m0[j] = e01[j>>2]*e23[j&3];
        }
        {
            const float e01[4] = {c4[4]*c4[5], c4[4]*s4[5], s4[4]*c4[5], s4[4]*s4[5]};
            const float e23[4] = {c4[6]*c4[7], c4[6]*s4[7], s4[6]*c4[7], s4[6]*s4[7]};
            #pragma unroll
            for (int j = 0; j < 16; ++j) m1[j] = e01[j>>2]*e23[j&3];
        }
    }

    // ---- wave 0: unitary -> V^T in block LDS ----
    if (wv == 0) {
        const int row = lane >> 2;
        const int cg  = lane & 3;
        float ur[4], ui[4];   // U[row][4cg+c]
        #pragma unroll
        for (int c = 0; c < 4; ++c) { ur[c] = (row == 4*cg + c) ? 1.f : 0.f; ui[c] = 0.f; }

        #pragma unroll
        for (int l = 0; l < 2; ++l) {
            #pragma unroll
            for (int w = 0; w < 4; ++w) {
                const float ph = wts[l*12 + w*3 + 0];
                const float th = wts[l*12 + w*3 + 1];
                const float om = wts[l*12 + w*3 + 2];
                float st, ct; __sincosf(0.5f*th, &st, &ct);
                float sp, cp; __sincosf(0.5f*(ph+om), &sp, &cp);
                float sm, cm; __sincosf(0.5f*(ph-om), &sm, &cm);
                const float a00r =  cp*ct, a00i = -sp*ct;
                const float a01r = -cm*st, a01i = -sm*st;
                const float a10r =  cm*st, a10i = -sm*st;
                const float a11r =  cp*ct, a11i =  sp*ct;
                const int m8 = 8 >> w;
                const int xm = m8 << 2;           // lane xor mask for row^m8
                const bool hi = (row & m8) != 0;
                #pragma unroll
                for (int c = 0; c < 4; ++c) {
                    const float pr = __shfl_xor(ur[c], xm, 64);
                    const float pi = __shfl_xor(ui[c], xm, 64);
                    float nr, ni;
                    if (!hi) {
                        nr = a00r*ur[c] - a00i*ui[c] + a01r*pr - a01i*pi;
                        ni = a00r*ui[c] + a00i*ur[c] + a01r*pi + a01i*pr;
                    } else {
                        nr = a11r*ur[c] - a11i*ui[c] + a10r*pr - a10i*pi;
                        ni = a11r*ui[c] + a11i*ur[c] + a10r*pi + a10i*pr;
                    }
                    ur[c] = nr; ui[c] = ni;
                }
            }
            const int rr = (l == 0) ? 1 : 2;
            #pragma unroll
            for (int w = 0; w < 4; ++w) {
                const int cmk = 8 >> w;
                const int tmk = 8 >> ((w + rr) & 3);
                const int src = (row & cmk) ? (row ^ tmk) : row;
                const int srcLane = src*4 + cg;
                #pragma unroll
                for (int c = 0; c < 4; ++c) {
                    ur[c] = __shfl(ur[c], srcLane, 64);
                    ui[c] = __shfl(ui[c], srcLane, 64);
                }
            }
        }

        // V = U * diag((-i)^popc(col)); park transposed in block LDS
        #pragma unroll
        for (int c = 0; c < 4; ++c) {
            const int col = 4*cg + c;
            const int p = __popc(col) & 3;
            float vr, vi;
            if (p == 0)      { vr =  ur[c]; vi =  ui[c]; }
            else if (p == 1) { vr =  ui[c]; vi = -ur[c]; }
            else if (p == 2) { vr = -ur[c]; vi = -ui[c]; }
            else             { vr = -ui[c]; vi =  ur[c]; }
            wlds[WS_VRT + col*16 + row] = vr;
            wlds[WS_VIT + col*16 + row] = vi;
        }
    } else if (wv == 1) {
        // ---- wave 1 (concurrent with wave 0): LN constants ----
        const int k = lane;
        const float4 wk = ((const float4*)W)[k];
        const float w0 = wk.x, w1 = wk.y, w2 = wk.z, w3 = wk.w;
        const float bk = bias[k];
        auto wsum = [](float v) {
            #pragma unroll
            for (int o = 32; o; o >>= 1) v += __shfl_xor(v, o, 64);
            return v;
        };
        const float inv64 = 1.f/64.f;
        const float mw0 = wsum(w0)*inv64, mw1 = wsum(w1)*inv64;
        const float mw2 = wsum(w2)*inv64, mw3 = wsum(w3)*inv64;
        const float bm = wsum(bk)*inv64;
        float cc[4] = {w0-mw0, w1-mw1, w2-mw2, w3-mw3};
        const float bc = bk - bm;
        const float gk = gamma[k];
        float4 av;
        av.x = cc[0]*gk; av.y = cc[1]*gk; av.z = cc[2]*gk; av.w = cc[3]*gk;
        ((float4*)(wlds + WS_A))[k] = av;
        wlds[WS_B0 + k] = bc*gk;
        // G is symmetric: 10 wave-sums instead of 16
        #pragma unroll
        for (int a = 0; a < 4; ++a)
            #pragma unroll
            for (int b2 = a; b2 < 4; ++b2) {
                const float s = wsum(cc[a]*cc[b2])*inv64;   // wave-uniform
                if (k == 0) {
                    wlds[WS_G + a*4 + b2] = s;
                    wlds[WS_G + b2*4 + a] = s;
                }
            }
        #pragma unroll
        for (int a = 0; a < 4; ++a) {
            const float s = wsum(bc*cc[a])*inv64;
            if (k == 0) wlds[WS_g + a] = s;
        }
        { const float s = wsum(bc*bc)*inv64; if (k == 0) wlds[WS_C0] = s; }
    }

    __syncthreads();   // the ONLY barrier: setup results now block-visible

    // store-phase constants (need the barrier for WS_A/WS_B0)
    float4 A4[4];
    #pragma unroll
    for (int u = 0; u < 4; ++u) A4[u] = ((const float4*)(wlds + WS_A))[k4t*4 + u];
    const float4 B04v = ((const float4*)(wlds + WS_B0))[k4t];
    const float B04[4] = {B04v.x, B04v.y, B04v.z, B04v.w};
    const float Bt4[4] = {Bt4v.x, Bt4v.y, Bt4v.z, Bt4v.w};

    const float4* vr4 = (const float4*)(wlds + WS_VRT);
    const float4* vi4 = (const float4*)(wlds + WS_VIT);

    // per-sample matvec: j-outer, FMA order identical to R6/R7
    auto matvec = [&](const float* m, float* r, float* si) {
        #pragma unroll
        for (int i = 0; i < 16; ++i) { r[i] = 0.f; si[i] = 0.f; }
        #pragma unroll
        for (int j = 0; j < 16; ++j) {
            const float mj = m[j];
            #pragma unroll
            for (int i4 = 0; i4 < 4; ++i4) {
                const float4 a = vr4[j*4 + i4];   // uniform-address broadcast
                const float4 b = vi4[j*4 + i4];
                r [i4*4+0] = fmaf(a.x, mj, r [i4*4+0]);
                r [i4*4+1] = fmaf(a.y, mj, r [i4*4+1]);
                r [i4*4+2] = fmaf(a.z, mj, r [i4*4+2]);
                r [i4*4+3] = fmaf(a.w, mj, r [i4*4+3]);
                si[i4*4+0] = fmaf(b.x, mj, si[i4*4+0]);
                si[i4*4+1] = fmaf(b.y, mj, si[i4*4+1]);
                si[i4*4+2] = fmaf(b.z, mj, si[i4*4+2]);
                si[i4*4+3] = fmaf(b.w, mj, si[i4*4+3]);
            }
        }
    };

    // finish (z -> softmax -> var -> inv), identical math per sample
    auto finish = [&](const float* r, const float* si, float4& qo, float& invo) {
        float z0 = 0.f, z1 = 0.f, z2 = 0.f, z3 = 0.f;
        #pragma unroll
        for (int i = 0; i < 16; ++i) {
            const float p = r[i]*r[i] + si[i]*si[i];
            z0 += (i & 8) ? -p : p;
            z1 += (i & 4) ? -p : p;
            z2 += (i & 2) ? -p : p;
            z3 += (i & 1) ? -p : p;
        }
        const float mx = fmaxf(fmaxf(z0, z1), fmaxf(z2, z3));
        const float e0 = __expf(z0-mx), e1 = __expf(z1-mx);
        const float e2 = __expf(z2-mx), e3 = __expf(z3-mx);
        const float rs = 1.f / (e0+e1+e2+e3);
        const float qx = e0*rs, qy = e1*rs, qz = e2*rs, qw = e3*rs;
        float var = wlds[WS_C0];
        {
            const float4 Gs0 = ((const float4*)(wlds + WS_G))[0];
            const float4 Gs1 = ((const float4*)(wlds + WS_G))[1];
            const float4 Gs2 = ((const float4*)(wlds + WS_G))[2];
            const float4 Gs3 = ((const float4*)(wlds + WS_G))[3];
            const float4 gv  = ((const float4*)(wlds + WS_g))[0];
            const float qa[4] = {qx, qy, qz, qw};
            const float4 Gs[4] = {Gs0, Gs1, Gs2, Gs3};
            const float ga[4] = {gv.x, gv.y, gv.z, gv.w};
            #pragma unroll
            for (int a = 0; a < 4; ++a) {
                float t = 2.f * ga[a];
                t = fmaf(Gs[a].x, qa[0], t);
                t = fmaf(Gs[a].y, qa[1], t);
                t = fmaf(Gs[a].z, qa[2], t);
                t = fmaf(Gs[a].w, qa[3], t);
                var = fmaf(qa[a], t, var);
            }
        }
        qo = make_float4(qx, qy, qz, qw);
        invo = rsqrtf(var + 1e-5f);
    };

    // 16 coalesced store iterations for one 64-sample half
    // (half h covers local samples [wv*128 + h*64, +64))
    float4* outv = (float4*)out + (size_t)blockIdx.x * 8192 + wv * 2048 + lane;
    auto store_half = [&](int h) {
        const float4* qld = (const float4*)(wlds + WS_Q) + wv*128 + h*64 + (lane >> 4);
        const float*  ild = wlds + WS_INV + wv*128 + h*64 + (lane >> 4);
        float4* ov = outv + h*1024;
        #pragma unroll
        for (int iter = 0; iter < 16; ++iter) {
            const float4 q  = qld[iter*4];     // 4 addrs/wave, conflict-free
            const float  iv = ild[iter*4];
            float4 o;
            float* op = (float*)&o;
            #pragma unroll
            for (int u = 0; u < 4; ++u) {
                float t = B04[u];
                t = fmaf(A4[u].x, q.x, t);
                t = fmaf(A4[u].y, q.y, t);
                t = fmaf(A4[u].z, q.z, t);
                t = fmaf(A4[u].w, q.w, t);
                op[u] = fmaf(t, iv, Bt4[u]);
            }
            ov[iter*64] = o;
        }
    };

    // ---- pipelined pass 0: sample 0 compute -> stage -> store ----
    {
        float r[16], t[16];
        matvec(m0, r, t);
        float4 q; float inv;
        finish(r, t, q, inv);
        // wave-local staging: same-wave RAW ordered by lgkmcnt, no barrier
        ((float4*)(wlds + WS_Q))[wv*128 + lane] = q;
        wlds[WS_INV + wv*128 + lane] = inv;
        store_half(0);
    }

    // ---- pipelined pass 1: sample 1 compute -> stage -> store ----
    {
        float r[16], t[16];
        matvec(m1, r, t);
        float4 q; float inv;
        finish(r, t, q, inv);
        ((float4*)(wlds + WS_Q))[wv*128 + 64 + lane] = q;
        wlds[WS_INV + wv*128 + 64 + lane] = inv;
        store_half(1);
    }
}

extern "C" void kernel_launch(void* const* d_in, const int* in_sizes, int n_in,
                              void* d_out, int out_size, void* d_ws, size_t ws_size,
                              hipStream_t stream) {
    const float* x     = (const float*)d_in[0];
    const float* wts   = (const float*)d_in[1];
    const float* W     = (const float*)d_in[2];
    const float* bias  = (const float*)d_in[3];
    const float* gamma = (const float*)d_in[4];
    const float* beta  = (const float*)d_in[5];
    float* out = (float*)d_out;
    const int B = in_sizes[0] / 4;   // 262144

    hipLaunchKernelGGL(qb_fused, dim3(B / 512), dim3(256), 0, stream,
                       x, wts, W, bias, gamma, beta, out);
}